// Round 1
// baseline (25.072 us; speedup 1.0000x reference)
//
#include <hip/hip_runtime.h>

namespace {

constexpr int T = 64;
constexpr int B = 65536;
constexpr int C = 32;
constexpr int NT = 6;
constexpr int HALF_C = 16;        // channels per thread (2 threads per b)
constexpr int BLOCK = 256;

__global__ __launch_bounds__(BLOCK) void trust_kernel(
    const int2* __restrict__ perf,    // [T*B] (x = failure flag, y = success flag)
    const int*  __restrict__ obsids,  // [T*B]
    const int*  __restrict__ predids, // [B]
    const float* __restrict__ obsM,   // [C*NT] row-major [C][NT]
    float* __restrict__ out)          // [B]
{
    // obsMatrix staged in LDS with row stride 8 (pad 6->8) so the per-id
    // gather lobs[c*8 + id] spreads across banks (<=2 distinct addrs/bank).
    __shared__ float lobs[C * 8];
    const int tid = threadIdx.x;
    if (tid < C * NT) {
        const int c = tid / NT;
        const int j = tid - c * NT;
        lobs[c * 8 + j] = obsM[tid];
    }
    __syncthreads();

    const int gid   = blockIdx.x * BLOCK + tid;
    const int b     = gid >> 1;       // sequence index
    const int half  = gid & 1;        // which 16 channels this thread owns
    const int cbase = half * HALF_C;

    float mean[HALF_C];
#pragma unroll
    for (int c = 0; c < HALF_C; ++c) mean[c] = 0.0f;

    const float INF = __builtin_inff();

    // One step of the fold:
    //   success: mean = max(mean, cap)  -> med3(mean, +INF, cap)
    //   failure: mean = min(mean, cap)  -> med3(mean, -INF, cap)
    //   noop:    mean unchanged         -> med3(mean, -INF, +INF)
#define STEP(PF, ID)                                                       \
    do {                                                                   \
        const bool s_   = ((PF).x == 0) & ((PF).y != 0);                   \
        const bool f_   = ((PF).x != 0) & ((PF).y == 0);                   \
        const bool act_ = s_ | f_;                                         \
        const float aa_ = s_ ? INF : -INF;                                 \
        const float in_ = -aa_;                                            \
        _Pragma("unroll")                                                  \
        for (int c = 0; c < HALF_C; ++c) {                                 \
            const float cap_ = lobs[(cbase + c) * 8 + (ID)];               \
            const float bb_  = act_ ? cap_ : in_;                          \
            mean[c] = __builtin_amdgcn_fmed3f(mean[c], aa_, bb_);          \
        }                                                                  \
    } while (0)

    // software-pipelined t-loop: prefetch next perf/id one iteration ahead
    int2 pf = perf[b];
    int  id = obsids[b];

#pragma unroll 4
    for (int t = 0; t < T - 1; ++t) {
        const int2 pf_n = perf[(t + 1) * B + b];
        const int  id_n = obsids[(t + 1) * B + b];
        STEP(pf, id);
        pf = pf_n;
        id = id_n;
    }
    STEP(pf, id);
#undef STEP

    // trust predicate over this thread's 16 channels
    const int pid = predids[b];
    bool ok = true;
#pragma unroll
    for (int c = 0; c < HALF_C; ++c) {
        const float req = lobs[(cbase + c) * 8 + pid];
        ok &= (req <= mean[c]);
    }

    // combine the two halves of each b (lanes 2k and 2k+1 of the same wave)
    const unsigned long long bal = __ballot(ok);
    const int lane = tid & 63;
    const bool other = (bal >> (lane ^ 1)) & 1ull;
    if (half == 0) {
        out[b] = (ok && other) ? 1.0f : 0.0f;
    }
}

}  // namespace

extern "C" void kernel_launch(void* const* d_in, const int* in_sizes, int n_in,
                              void* d_out, int out_size, void* d_ws, size_t ws_size,
                              hipStream_t stream) {
    const int2*  perf    = (const int2*)d_in[0];   // inptasksperf [T,B,2] int32
    const int*   obsids  = (const int*)d_in[1];    // tasksobsids  [T,B,1] int32
    const int*   predids = (const int*)d_in[2];    // taskspredids [B,1]   int32
    const float* obsM    = (const float*)d_in[3];  // obsMatrix    [C,NT]  f32
    float*       out     = (float*)d_out;          // trust        [B,1]   f32

    const int total_threads = 2 * B;               // 2 threads per sequence
    dim3 grid(total_threads / BLOCK), block(BLOCK);
    trust_kernel<<<grid, block, 0, stream>>>(perf, obsids, predids, obsM, out);
}

// Round 2
// 21.009 us; speedup vs baseline: 1.1934x; 1.1934x over previous
//
#include <hip/hip_runtime.h>

namespace {

constexpr int T = 64;
constexpr int B = 65536;
constexpr int C = 32;
constexpr int NT = 6;
constexpr int PER = 8;          // channels per thread (4 threads per b)
constexpr int BLOCK = 256;
constexpr int STRIDE = 40;      // f32 words per LDS column (32 data + 8 pad)
constexpr int NCOL = 7;         // 6 real columns + 1 dummy (-inf) for noop steps

// LDS layout: column j occupies words [j*40, j*40+32) with channel permutation
//   pos(c) = 16*q + 4*p + r   where p = c/8, q = (c%8)/4, r = c%4
// Thread "p" (gid&3) owns channels c = 8p + {0..7}; its two 16B reads start at
// byte addr col*160 + p*16 (+64 for q=1). Per-instruction bank starts
// (8*id + 4*p) mod 32 cover {0,4,...,28} with <=2 distinct addrs each
// -> 2-way aliasing, which is free on CDNA4.
__global__ __launch_bounds__(BLOCK) void trust_kernel(
    const int2* __restrict__ perf,    // [T*B] (x = failure flag, y = success flag)
    const int*  __restrict__ obsids,  // [T*B]
    const int*  __restrict__ predids, // [B]
    const float* __restrict__ obsM,   // [C*NT] row-major [C][NT]
    float* __restrict__ out)          // [B]
{
    __shared__ float lobs[NCOL * STRIDE];
    const int tid = threadIdx.x;
    const float PINF = __builtin_inff();
    const float NINF = -PINF;

    for (int i = tid; i < NCOL * STRIDE; i += BLOCK) {
        const int j = i / STRIDE;
        const int w = i - j * STRIDE;
        float v = NINF;                       // dummy column / pad
        if (j < NT && w < C) {
            const int q = w >> 4;
            const int p = (w >> 2) & 3;
            const int r = w & 3;
            const int c = 8 * p + 4 * q + r;  // channel stored at this word
            v = obsM[c * NT + j];
        }
        lobs[i] = v;
    }
    __syncthreads();

    const int gid   = blockIdx.x * BLOCK + tid;
    const int b     = gid >> 2;       // sequence index
    const int p     = gid & 3;        // which 8 channels this thread owns
    const int pbyte = p * 16;
    const char* lbase = (const char*)lobs;

    float mean[PER];
#pragma unroll
    for (int k = 0; k < PER; ++k) mean[k] = 0.0f;

    const int2* pf_ptr = perf + b;
    const int*  id_ptr = obsids + b;

    // One fold step, 1 med3 per channel:
    //   success (y!=0): aa=+INF, col=id   -> med3(m,+INF,cap) = max(m,cap)
    //   failure (x!=0): aa=-INF, col=id   -> med3(m,-INF,cap) = min(m,cap)
    //   noop:           aa=+INF, col=6(-INF) -> med3(m,+INF,-INF) = m
#define STEP(PF, ID)                                                        \
    do {                                                                    \
        const float aa_  = ((PF).x != 0) ? NINF : PINF;                     \
        const int   off_ = ((((PF).x | (PF).y) != 0) ? (ID) * 160 : 960)    \
                           + pbyte;                                         \
        const float4 ca_ = *(const float4*)(lbase + off_);                  \
        const float4 cb_ = *(const float4*)(lbase + off_ + 64);             \
        mean[0] = __builtin_amdgcn_fmed3f(mean[0], aa_, ca_.x);             \
        mean[1] = __builtin_amdgcn_fmed3f(mean[1], aa_, ca_.y);             \
        mean[2] = __builtin_amdgcn_fmed3f(mean[2], aa_, ca_.z);             \
        mean[3] = __builtin_amdgcn_fmed3f(mean[3], aa_, ca_.w);             \
        mean[4] = __builtin_amdgcn_fmed3f(mean[4], aa_, cb_.x);             \
        mean[5] = __builtin_amdgcn_fmed3f(mean[5], aa_, cb_.y);             \
        mean[6] = __builtin_amdgcn_fmed3f(mean[6], aa_, cb_.z);             \
        mean[7] = __builtin_amdgcn_fmed3f(mean[7], aa_, cb_.w);             \
    } while (0)

    int2 pf = pf_ptr[0];
    int  id = id_ptr[0];

#pragma unroll 4
    for (int t = 0; t < T - 1; ++t) {
        const int2 pf_n = pf_ptr[(t + 1) * B];
        const int  id_n = id_ptr[(t + 1) * B];
        STEP(pf, id);
        pf = pf_n;
        id = id_n;
    }
    STEP(pf, id);
#undef STEP

    // trust predicate over this thread's 8 channels
    const int pid = predids[b];
    const float4 ra = *(const float4*)(lbase + pid * 160 + pbyte);
    const float4 rb = *(const float4*)(lbase + pid * 160 + pbyte + 64);
    bool ok = (ra.x <= mean[0]) & (ra.y <= mean[1]) &
              (ra.z <= mean[2]) & (ra.w <= mean[3]) &
              (rb.x <= mean[4]) & (rb.y <= mean[5]) &
              (rb.z <= mean[6]) & (rb.w <= mean[7]);

    // combine the 4 threads of each b (lanes 4k..4k+3 of the same wave)
    const unsigned long long bal = __ballot(ok);
    const int lane = tid & 63;
    const int grp  = lane & ~3;
    if (p == 0) {
        out[b] = (((bal >> grp) & 0xFull) == 0xFull) ? 1.0f : 0.0f;
    }
}

}  // namespace

extern "C" void kernel_launch(void* const* d_in, const int* in_sizes, int n_in,
                              void* d_out, int out_size, void* d_ws, size_t ws_size,
                              hipStream_t stream) {
    const int2*  perf    = (const int2*)d_in[0];   // inptasksperf [T,B,2] int32
    const int*   obsids  = (const int*)d_in[1];    // tasksobsids  [T,B,1] int32
    const int*   predids = (const int*)d_in[2];    // taskspredids [B,1]   int32
    const float* obsM    = (const float*)d_in[3];  // obsMatrix    [C,NT]  f32
    float*       out     = (float*)d_out;          // trust        [B,1]   f32

    const int total_threads = 4 * B;               // 4 threads per sequence
    dim3 grid(total_threads / BLOCK), block(BLOCK);
    trust_kernel<<<grid, block, 0, stream>>>(perf, obsids, predids, obsM, out);
}